// Round 1
// baseline (4384.545 us; speedup 1.0000x reference)
//
#include <hip/hip_runtime.h>

#define B_NODES 20000
#define N1_NODES 80000
#define NTOT 100000            // B + N1
#define E_EDGES 800000
#define CIN 256
#define COUT 256
#define NUM_D 32
#define NB 8                   // CIN / NUM_D
#define NUM_M 4096
#define NUM_N 200000

// ---------------------------------------------------------------------------
// init: x_output[r][c] = b_conv[c]  (bias folded into segment-sum), scal = 0
// ---------------------------------------------------------------------------
__global__ __launch_bounds__(256) void init_xout_kernel(
    const float* __restrict__ b_conv, float* __restrict__ xout,
    float* __restrict__ scal)
{
    const float4* bc4 = (const float4*)b_conv;   // 64 float4 per row
    size_t total4 = (size_t)NTOT * 64;
    for (size_t i = (size_t)blockIdx.x * blockDim.x + threadIdx.x;
         i < total4; i += (size_t)gridDim.x * blockDim.x) {
        ((float4*)xout)[i] = bc4[i & 63];
    }
    if (blockIdx.x == 0 && threadIdx.x == 0) scal[0] = 0.0f;
}

// ---------------------------------------------------------------------------
// GEMM 1: xw = x_input @ W_conv, with x_input rows >= B gathered from codebook
// 64x64 tile, 256 threads (16x16), 4x4 outputs/thread, BK=64
// grid: (ceil(NTOT/64), 4)
// ---------------------------------------------------------------------------
__global__ __launch_bounds__(256) void gemm_xinput_kernel(
    const float* __restrict__ x, const int* __restrict__ fo,
    const int* __restrict__ cind, const float* __restrict__ cb,
    const float* __restrict__ W, float* __restrict__ xw)
{
    __shared__ float As[64][65];
    __shared__ float Bs[64][65];

    const int row0 = blockIdx.x * 64;
    const int col0 = blockIdx.y * 64;
    const int tid = threadIdx.x;
    const int tr = tid >> 4;          // 0..15
    const int tc = tid & 15;          // 0..15

    float acc[4][4] = {};

    for (int k0 = 0; k0 < CIN; k0 += 64) {
        // load A tile (with gather for rows >= B_NODES)
        #pragma unroll
        for (int l = 0; l < 16; ++l) {
            int idx = tid + l * 256;          // 0..4095
            int r = idx >> 6, c = idx & 63;
            int grow = row0 + r;
            int gcol = k0 + c;
            float v = 0.0f;
            if (grow < NTOT) {
                if (grow < B_NODES) {
                    v = x[(size_t)grow * CIN + gcol];
                } else {
                    int i = grow - B_NODES;
                    int b = gcol >> 5, d = gcol & 31;
                    int idx2 = fo[i];
                    int cidx = cind[b * NUM_N + idx2];
                    v = cb[((size_t)(b * NUM_M + cidx)) * (2 * NUM_D) + d];
                }
            }
            As[r][c] = v;
        }
        // load B tile
        #pragma unroll
        for (int l = 0; l < 16; ++l) {
            int idx = tid + l * 256;
            int r = idx >> 6, c = idx & 63;
            Bs[r][c] = W[(size_t)(k0 + r) * COUT + col0 + c];
        }
        __syncthreads();

        #pragma unroll
        for (int kk = 0; kk < 64; ++kk) {
            float a[4], b[4];
            #pragma unroll
            for (int i = 0; i < 4; ++i) a[i] = As[tr * 4 + i][kk];
            #pragma unroll
            for (int j = 0; j < 4; ++j) b[j] = Bs[kk][tc * 4 + j];
            #pragma unroll
            for (int i = 0; i < 4; ++i)
                #pragma unroll
                for (int j = 0; j < 4; ++j)
                    acc[i][j] += a[i] * b[j];
        }
        __syncthreads();
    }

    #pragma unroll
    for (int i = 0; i < 4; ++i) {
        int grow = row0 + tr * 4 + i;
        if (grow >= NTOT) continue;
        #pragma unroll
        for (int j = 0; j < 4; ++j) {
            xw[(size_t)grow * COUT + col0 + tc * 4 + j] = acc[i][j];
        }
    }
}

// ---------------------------------------------------------------------------
// edge scatter: x_output[dst] += xw[src] * w   (atomic, 64 lanes per edge)
// block = 256 threads = 4 edges
// ---------------------------------------------------------------------------
__global__ __launch_bounds__(256) void edge_scatter_kernel(
    const float* __restrict__ xw, const int* __restrict__ ei,
    const float* __restrict__ ew, float* __restrict__ xout)
{
    int eid = blockIdx.x * 4 + (threadIdx.x >> 6);
    if (eid >= E_EDGES) return;
    int lane = threadIdx.x & 63;
    int src = ei[eid];
    int dst = ei[E_EDGES + eid];
    float w = ew[eid];
    float4 v = ((const float4*)(xw + (size_t)src * CIN))[lane];
    float* d = xout + (size_t)dst * CIN + lane * 4;
    atomicAdd(d + 0, v.x * w);
    atomicAdd(d + 1, v.y * w);
    atomicAdd(d + 2, v.z * w);
    atomicAdd(d + 3, v.w * w);
}

// ---------------------------------------------------------------------------
// info reduction: scal += sum_i dot(x_output[B+i], grad[i])
// grad recomputed from codebook (cols 32..63). 1024 blocks, grid-stride rows.
// ---------------------------------------------------------------------------
__global__ __launch_bounds__(256) void info_kernel(
    const float* __restrict__ xout, const int* __restrict__ fo,
    const int* __restrict__ cind, const float* __restrict__ cb,
    float* __restrict__ scal)
{
    const int c = threadIdx.x;
    const int b = c >> 5, d = c & 31;
    float v = 0.0f;
    for (int i = blockIdx.x; i < N1_NODES; i += gridDim.x) {
        int idx2 = fo[i];
        int cidx = cind[b * NUM_N + idx2];
        float g = cb[((size_t)(b * NUM_M + cidx)) * (2 * NUM_D) + NUM_D + d];
        v += xout[(size_t)(B_NODES + i) * CIN + c] * g;
    }
    // wave reduce (64 lanes)
    #pragma unroll
    for (int off = 32; off > 0; off >>= 1) v += __shfl_down(v, off, 64);
    __shared__ float wsum[4];
    if ((threadIdx.x & 63) == 0) wsum[threadIdx.x >> 6] = v;
    __syncthreads();
    if (threadIdx.x == 0)
        atomicAdd(scal, wsum[0] + wsum[1] + wsum[2] + wsum[3]);
}

// ---------------------------------------------------------------------------
// GEMM 2 (fused): out = x_output[:B] @ W_t + x @ W_skip + (b_t + b_skip)
// virtual K = 512. Same 64x64 tiling. grid: (ceil(B/64), 4)
// ---------------------------------------------------------------------------
__global__ __launch_bounds__(256) void gemm_out_kernel(
    const float* __restrict__ xout, const float* __restrict__ x,
    const float* __restrict__ Wt, const float* __restrict__ Wskip,
    const float* __restrict__ bt, const float* __restrict__ bskip,
    float* __restrict__ out)
{
    __shared__ float As[64][65];
    __shared__ float Bs[64][65];

    const int row0 = blockIdx.x * 64;
    const int col0 = blockIdx.y * 64;
    const int tid = threadIdx.x;
    const int tr = tid >> 4;
    const int tc = tid & 15;

    float acc[4][4] = {};

    for (int k0 = 0; k0 < 512; k0 += 64) {
        #pragma unroll
        for (int l = 0; l < 16; ++l) {
            int idx = tid + l * 256;
            int r = idx >> 6, c = idx & 63;
            int grow = row0 + r;
            int gk = k0 + c;
            float v = 0.0f;
            if (grow < B_NODES) {
                v = (gk < 256) ? xout[(size_t)grow * CIN + gk]
                               : x[(size_t)grow * CIN + (gk - 256)];
            }
            As[r][c] = v;
        }
        #pragma unroll
        for (int l = 0; l < 16; ++l) {
            int idx = tid + l * 256;
            int r = idx >> 6, c = idx & 63;
            int gk = k0 + r;
            Bs[r][c] = (gk < 256) ? Wt[(size_t)gk * COUT + col0 + c]
                                  : Wskip[(size_t)(gk - 256) * COUT + col0 + c];
        }
        __syncthreads();

        #pragma unroll
        for (int kk = 0; kk < 64; ++kk) {
            float a[4], b[4];
            #pragma unroll
            for (int i = 0; i < 4; ++i) a[i] = As[tr * 4 + i][kk];
            #pragma unroll
            for (int j = 0; j < 4; ++j) b[j] = Bs[kk][tc * 4 + j];
            #pragma unroll
            for (int i = 0; i < 4; ++i)
                #pragma unroll
                for (int j = 0; j < 4; ++j)
                    acc[i][j] += a[i] * b[j];
        }
        __syncthreads();
    }

    #pragma unroll
    for (int i = 0; i < 4; ++i) {
        int grow = row0 + tr * 4 + i;
        if (grow >= B_NODES) continue;
        #pragma unroll
        for (int j = 0; j < 4; ++j) {
            int gcol = col0 + tc * 4 + j;
            out[(size_t)grow * COUT + gcol] = acc[i][j] + bt[gcol] + bskip[gcol];
        }
    }
}

// ---------------------------------------------------------------------------
// finalize scalar
// ---------------------------------------------------------------------------
__global__ void finalize_kernel(const float* __restrict__ scal,
                                const float* __restrict__ wur,
                                float* __restrict__ out)
{
    if (blockIdx.x == 0 && threadIdx.x == 0)
        out[(size_t)B_NODES * COUT] = scal[0] * wur[0];
}

// ---------------------------------------------------------------------------
extern "C" void kernel_launch(void* const* d_in, const int* in_sizes, int n_in,
                              void* d_out, int out_size, void* d_ws, size_t ws_size,
                              hipStream_t stream)
{
    const float* x       = (const float*)d_in[0];
    const float* ew      = (const float*)d_in[1];
    const float* cb      = (const float*)d_in[2];
    const float* W_conv  = (const float*)d_in[3];
    const float* b_conv  = (const float*)d_in[4];
    const float* W_t     = (const float*)d_in[5];
    const float* b_t     = (const float*)d_in[6];
    const float* W_skip  = (const float*)d_in[7];
    const float* b_skip  = (const float*)d_in[8];
    const float* wur     = (const float*)d_in[9];
    const int*   cind    = (const int*)d_in[10];
    const int*   fo      = (const int*)d_in[11];
    const int*   ei      = (const int*)d_in[12];

    float* out = (float*)d_out;

    // workspace layout: xw (25.6M f32) | x_output (25.6M f32) | scal (1 f32)
    float* xw   = (float*)d_ws;
    float* xout = xw + (size_t)NTOT * CIN;
    float* scal = xout + (size_t)NTOT * CIN;

    // 1. init x_output = b_conv (broadcast), scal = 0
    init_xout_kernel<<<2048, 256, 0, stream>>>(b_conv, xout, scal);

    // 2. xw = x_input @ W_conv (gather fused)
    {
        dim3 grid((NTOT + 63) / 64, COUT / 64);
        gemm_xinput_kernel<<<grid, 256, 0, stream>>>(x, fo, cind, cb, W_conv, xw);
    }

    // 3. edge scatter
    edge_scatter_kernel<<<E_EDGES / 4, 256, 0, stream>>>(xw, ei, ew, xout);

    // 4. info reduction
    info_kernel<<<1024, 256, 0, stream>>>(xout, fo, cind, cb, scal);

    // 5. out = x_output[:B] @ W_t + x @ W_skip + biases
    {
        dim3 grid((B_NODES + 63) / 64, COUT / 64);
        gemm_out_kernel<<<grid, 256, 0, stream>>>(xout, x, W_t, W_skip, b_t, b_skip, out);
    }

    // 6. scalar output
    finalize_kernel<<<1, 64, 0, stream>>>(scal, wur, out);
}

// Round 2
// 1973.517 us; speedup vs baseline: 2.2217x; 2.2217x over previous
//
#include <hip/hip_runtime.h>

#define B_NODES 20000
#define N1_NODES 80000
#define NTOT 100000            // B + N1
#define E_EDGES 800000
#define CIN 256
#define COUT 256
#define NUM_D 32
#define NB 8                   // CIN / NUM_D
#define NUM_M 4096
#define NUM_N 200000
#define NPART 2048             // scalar partial buckets

// ---------------------------------------------------------------------------
// GEMM 1: xw = x_input @ W_conv, with x_input rows >= B gathered from codebook
// ---------------------------------------------------------------------------
__global__ __launch_bounds__(256) void gemm_xinput_kernel(
    const float* __restrict__ x, const int* __restrict__ fo,
    const int* __restrict__ cind, const float* __restrict__ cb,
    const float* __restrict__ W, float* __restrict__ xw)
{
    __shared__ float As[64][65];
    __shared__ float Bs[64][65];

    const int row0 = blockIdx.x * 64;
    const int col0 = blockIdx.y * 64;
    const int tid = threadIdx.x;
    const int tr = tid >> 4;          // 0..15
    const int tc = tid & 15;          // 0..15

    float acc[4][4] = {};

    for (int k0 = 0; k0 < CIN; k0 += 64) {
        #pragma unroll
        for (int l = 0; l < 16; ++l) {
            int idx = tid + l * 256;          // 0..4095
            int r = idx >> 6, c = idx & 63;
            int grow = row0 + r;
            int gcol = k0 + c;
            float v = 0.0f;
            if (grow < NTOT) {
                if (grow < B_NODES) {
                    v = x[(size_t)grow * CIN + gcol];
                } else {
                    int i = grow - B_NODES;
                    int b = gcol >> 5, d = gcol & 31;
                    int idx2 = fo[i];
                    int cidx = cind[b * NUM_N + idx2];
                    v = cb[((size_t)(b * NUM_M + cidx)) * (2 * NUM_D) + d];
                }
            }
            As[r][c] = v;
        }
        #pragma unroll
        for (int l = 0; l < 16; ++l) {
            int idx = tid + l * 256;
            int r = idx >> 6, c = idx & 63;
            Bs[r][c] = W[(size_t)(k0 + r) * COUT + col0 + c];
        }
        __syncthreads();

        #pragma unroll
        for (int kk = 0; kk < 64; ++kk) {
            float a[4], b[4];
            #pragma unroll
            for (int i = 0; i < 4; ++i) a[i] = As[tr * 4 + i][kk];
            #pragma unroll
            for (int j = 0; j < 4; ++j) b[j] = Bs[kk][tc * 4 + j];
            #pragma unroll
            for (int i = 0; i < 4; ++i)
                #pragma unroll
                for (int j = 0; j < 4; ++j)
                    acc[i][j] += a[i] * b[j];
        }
        __syncthreads();
    }

    #pragma unroll
    for (int i = 0; i < 4; ++i) {
        int grow = row0 + tr * 4 + i;
        if (grow >= NTOT) continue;
        #pragma unroll
        for (int j = 0; j < 4; ++j) {
            xw[(size_t)grow * COUT + col0 + tc * 4 + j] = acc[i][j];
        }
    }
}

// ---------------------------------------------------------------------------
// CSR build step 1: histogram of destinations
// ---------------------------------------------------------------------------
__global__ __launch_bounds__(256) void hist_kernel(
    const int* __restrict__ ei, int* __restrict__ deg)
{
    for (int e = blockIdx.x * 256 + threadIdx.x; e < E_EDGES;
         e += gridDim.x * 256) {
        atomicAdd(&deg[ei[E_EDGES + e]], 1);
    }
}

// ---------------------------------------------------------------------------
// CSR build step 2: exclusive scan of deg (100000) -> offs (100001)
// single block, 1024 threads, chunked sequential + Hillis-Steele on partials
// ---------------------------------------------------------------------------
__global__ __launch_bounds__(1024) void scan_kernel(
    const int* __restrict__ deg, int* __restrict__ offs)
{
    __shared__ int part[1024];
    const int t = threadIdx.x;
    const int CH = 98;                      // 1024*98 >= 100000
    int lo = t * CH;
    int hi = lo + CH; if (hi > NTOT) hi = NTOT;
    int s = 0;
    for (int i = lo; i < hi && i < NTOT; ++i) s += deg[i];
    part[t] = s;
    __syncthreads();
    for (int st = 1; st < 1024; st <<= 1) {
        int v = (t >= st) ? part[t - st] : 0;
        __syncthreads();
        part[t] += v;
        __syncthreads();
    }
    int run = (t > 0) ? part[t - 1] : 0;
    for (int i = lo; i < hi && i < NTOT; ++i) {
        offs[i] = run;
        run += deg[i];
    }
    if (t == 1023) offs[NTOT] = part[1023];
}

// ---------------------------------------------------------------------------
// CSR build step 3: scatter edges into buckets (consumes deg down to 0)
// ---------------------------------------------------------------------------
__global__ __launch_bounds__(256) void scatter_edges_kernel(
    const int* __restrict__ ei, const float* __restrict__ ew,
    const int* __restrict__ offs, int* __restrict__ deg,
    int* __restrict__ es, float* __restrict__ ewt)
{
    int e = blockIdx.x * 256 + threadIdx.x;
    if (e >= E_EDGES) return;
    int dst = ei[E_EDGES + e];
    int r = atomicSub(&deg[dst], 1);
    int pos = offs[dst] + r - 1;
    es[pos]  = ei[e];
    ewt[pos] = ew[e];
}

// ---------------------------------------------------------------------------
// gather-accumulate: one wave per destination node.
//   acc = b_conv + sum_{e in bucket} xw[src_e] * w_e     (registers, float4)
//   node <  B : write row to xout
//   node >= B : fused info_backward dot with grad from codebook ->
//               wave-reduce -> spread atomic into scalpart
// ---------------------------------------------------------------------------
__global__ __launch_bounds__(256) void gather_accum_kernel(
    const float* __restrict__ xw, const int* __restrict__ es,
    const float* __restrict__ ewt, const int* __restrict__ offs,
    const float* __restrict__ b_conv,
    const int* __restrict__ fo, const int* __restrict__ cind,
    const float* __restrict__ cb,
    float* __restrict__ xout, float* __restrict__ scalpart)
{
    const int wid  = threadIdx.x >> 6;
    const int lane = threadIdx.x & 63;
    const int node = blockIdx.x * 4 + wid;
    if (node >= NTOT) return;

    float4 acc = ((const float4*)b_conv)[lane];

    const int s = offs[node];
    const int e = offs[node + 1];
    for (int j = s; j < e; ++j) {
        int   src = es[j];
        float w   = ewt[j];
        float4 v = ((const float4*)(xw + (size_t)src * CIN))[lane];
        acc.x += v.x * w;
        acc.y += v.y * w;
        acc.z += v.z * w;
        acc.w += v.w * w;
    }

    if (node < B_NODES) {
        ((float4*)(xout + (size_t)node * CIN))[lane] = acc;
    } else {
        int i  = node - B_NODES;
        int c0 = lane * 4;
        int b  = c0 >> 5, d = c0 & 31;
        int cidx = cind[b * NUM_N + fo[i]];
        float4 g = *(const float4*)(cb +
            ((size_t)(b * NUM_M + cidx)) * (2 * NUM_D) + NUM_D + d);
        float v = acc.x * g.x + acc.y * g.y + acc.z * g.z + acc.w * g.w;
        #pragma unroll
        for (int off = 32; off > 0; off >>= 1) v += __shfl_down(v, off, 64);
        if (lane == 0)
            atomicAdd(&scalpart[(blockIdx.x * 4 + wid) & (NPART - 1)], v);
    }
}

// ---------------------------------------------------------------------------
// GEMM 2 (fused): out = x_output[:B] @ W_t + x @ W_skip + (b_t + b_skip)
// ---------------------------------------------------------------------------
__global__ __launch_bounds__(256) void gemm_out_kernel(
    const float* __restrict__ xout, const float* __restrict__ x,
    const float* __restrict__ Wt, const float* __restrict__ Wskip,
    const float* __restrict__ bt, const float* __restrict__ bskip,
    float* __restrict__ out)
{
    __shared__ float As[64][65];
    __shared__ float Bs[64][65];

    const int row0 = blockIdx.x * 64;
    const int col0 = blockIdx.y * 64;
    const int tid = threadIdx.x;
    const int tr = tid >> 4;
    const int tc = tid & 15;

    float acc[4][4] = {};

    for (int k0 = 0; k0 < 512; k0 += 64) {
        #pragma unroll
        for (int l = 0; l < 16; ++l) {
            int idx = tid + l * 256;
            int r = idx >> 6, c = idx & 63;
            int grow = row0 + r;
            int gk = k0 + c;
            float v = 0.0f;
            if (grow < B_NODES) {
                v = (gk < 256) ? xout[(size_t)grow * CIN + gk]
                               : x[(size_t)grow * CIN + (gk - 256)];
            }
            As[r][c] = v;
        }
        #pragma unroll
        for (int l = 0; l < 16; ++l) {
            int idx = tid + l * 256;
            int r = idx >> 6, c = idx & 63;
            int gk = k0 + r;
            Bs[r][c] = (gk < 256) ? Wt[(size_t)gk * COUT + col0 + c]
                                  : Wskip[(size_t)(gk - 256) * COUT + col0 + c];
        }
        __syncthreads();

        #pragma unroll
        for (int kk = 0; kk < 64; ++kk) {
            float a[4], b[4];
            #pragma unroll
            for (int i = 0; i < 4; ++i) a[i] = As[tr * 4 + i][kk];
            #pragma unroll
            for (int j = 0; j < 4; ++j) b[j] = Bs[kk][tc * 4 + j];
            #pragma unroll
            for (int i = 0; i < 4; ++i)
                #pragma unroll
                for (int j = 0; j < 4; ++j)
                    acc[i][j] += a[i] * b[j];
        }
        __syncthreads();
    }

    #pragma unroll
    for (int i = 0; i < 4; ++i) {
        int grow = row0 + tr * 4 + i;
        if (grow >= B_NODES) continue;
        #pragma unroll
        for (int j = 0; j < 4; ++j) {
            int gcol = col0 + tc * 4 + j;
            out[(size_t)grow * COUT + gcol] = acc[i][j] + bt[gcol] + bskip[gcol];
        }
    }
}

// ---------------------------------------------------------------------------
// finalize: out_scalar = sum(scalpart) * warm_up_rate
// ---------------------------------------------------------------------------
__global__ __launch_bounds__(256) void finalize_kernel(
    const float* __restrict__ scalpart, const float* __restrict__ wur,
    float* __restrict__ out)
{
    __shared__ float wsum[4];
    float v = 0.0f;
    for (int i = threadIdx.x; i < NPART; i += 256) v += scalpart[i];
    #pragma unroll
    for (int off = 32; off > 0; off >>= 1) v += __shfl_down(v, off, 64);
    if ((threadIdx.x & 63) == 0) wsum[threadIdx.x >> 6] = v;
    __syncthreads();
    if (threadIdx.x == 0)
        out[(size_t)B_NODES * COUT] =
            (wsum[0] + wsum[1] + wsum[2] + wsum[3]) * wur[0];
}

// ---------------------------------------------------------------------------
extern "C" void kernel_launch(void* const* d_in, const int* in_sizes, int n_in,
                              void* d_out, int out_size, void* d_ws, size_t ws_size,
                              hipStream_t stream)
{
    const float* x       = (const float*)d_in[0];
    const float* ew      = (const float*)d_in[1];
    const float* cb      = (const float*)d_in[2];
    const float* W_conv  = (const float*)d_in[3];
    const float* b_conv  = (const float*)d_in[4];
    const float* W_t     = (const float*)d_in[5];
    const float* b_t     = (const float*)d_in[6];
    const float* W_skip  = (const float*)d_in[7];
    const float* b_skip  = (const float*)d_in[8];
    const float* wur     = (const float*)d_in[9];
    const int*   cind    = (const int*)d_in[10];
    const int*   fo      = (const int*)d_in[11];
    const int*   ei      = (const int*)d_in[12];

    float* out = (float*)d_out;

    // workspace layout (float4-accessed arrays first for alignment)
    float* xw       = (float*)d_ws;                       // NTOT*CIN
    float* xout     = xw + (size_t)NTOT * CIN;            // B_NODES*CIN
    float* ewt      = xout + (size_t)B_NODES * CIN;       // E
    float* scalpart = ewt + E_EDGES;                      // NPART
    int*   es       = (int*)(scalpart + NPART);           // E
    int*   deg      = es + E_EDGES;                       // NTOT
    int*   offs     = deg + NTOT;                         // NTOT+1

    // zero deg + scalar partials
    hipMemsetAsync(deg, 0, sizeof(int) * NTOT, stream);
    hipMemsetAsync(scalpart, 0, sizeof(float) * NPART, stream);

    // CSR build
    hist_kernel<<<1024, 256, 0, stream>>>(ei, deg);
    scan_kernel<<<1, 1024, 0, stream>>>(deg, offs);
    scatter_edges_kernel<<<(E_EDGES + 255) / 256, 256, 0, stream>>>(
        ei, ew, offs, deg, es, ewt);

    // xw = x_input @ W_conv (gather fused)
    {
        dim3 grid((NTOT + 63) / 64, COUT / 64);
        gemm_xinput_kernel<<<grid, 256, 0, stream>>>(x, fo, cind, cb, W_conv, xw);
    }

    // per-destination gather + accumulate (+ fused info_backward)
    gather_accum_kernel<<<NTOT / 4, 256, 0, stream>>>(
        xw, es, ewt, offs, b_conv, fo, cind, cb, xout, scalpart);

    // out = x_output[:B] @ W_t + x @ W_skip + biases
    {
        dim3 grid((B_NODES + 63) / 64, COUT / 64);
        gemm_out_kernel<<<grid, 256, 0, stream>>>(xout, x, W_t, W_skip,
                                                  b_t, b_skip, out);
    }

    finalize_kernel<<<1, 256, 0, stream>>>(scalpart, wur, out);
}

// Round 3
// 481.438 us; speedup vs baseline: 9.1072x; 4.0992x over previous
//
#include <hip/hip_runtime.h>

#define B_NODES 20000
#define N1_NODES 80000
#define NTOT 100000            // B + N1
#define E_EDGES 800000
#define CIN 256
#define COUT 256
#define NUM_D 32
#define NB 8                   // CIN / NUM_D
#define NUM_M 4096
#define NUM_N 200000
#define NPART 2048             // scalar partial buckets

typedef __attribute__((ext_vector_type(8))) short short8;
typedef __attribute__((ext_vector_type(4))) float f32x4;

// f32 -> bf16 round-to-nearest-even
__device__ inline unsigned short f2bf(float f) {
    unsigned int u = __float_as_uint(f);
    u += 0x7FFFu + ((u >> 16) & 1u);
    return (unsigned short)(u >> 16);
}

__device__ inline short8 pack2(float4 a, float4 b) {
    short8 r;
    r[0] = (short)f2bf(a.x); r[1] = (short)f2bf(a.y);
    r[2] = (short)f2bf(a.z); r[3] = (short)f2bf(a.w);
    r[4] = (short)f2bf(b.x); r[5] = (short)f2bf(b.y);
    r[6] = (short)f2bf(b.z); r[7] = (short)f2bf(b.w);
    return r;
}

// ---------------------------------------------------------------------------
// transpose + convert: dst[n][colOff + k] = bf16(src[k][n]); src is [64*gx][256]
// grid (K/64, 256/64), 256 threads
// ---------------------------------------------------------------------------
__global__ __launch_bounds__(256) void transpose_cvt_kernel(
    const float* __restrict__ src, short* __restrict__ dst,
    int dstStride, int colOff)
{
    __shared__ float Ls[64][65];
    const int k0 = blockIdx.x * 64, n0 = blockIdx.y * 64;
    const int tid = threadIdx.x;
    #pragma unroll
    for (int lp = 0; lp < 16; ++lp) {
        int idx = tid + lp * 256;
        int rr = idx >> 6, cc = idx & 63;
        Ls[rr][cc] = src[(size_t)(k0 + rr) * 256 + n0 + cc];
    }
    __syncthreads();
    #pragma unroll
    for (int lp = 0; lp < 16; ++lp) {
        int idx = tid + lp * 256;
        int rr = idx >> 6, cc = idx & 63;
        dst[(size_t)(n0 + rr) * dstStride + colOff + k0 + cc] =
            (short)f2bf(Ls[cc][rr]);
    }
}

// ---------------------------------------------------------------------------
// GEMM 1 (MFMA bf16): xw = x_input @ W_conv
// tile 64(M) x 256(N), K-step 32, 4 waves (each owns 64 N-cols)
// A rows >= B_NODES gathered from codebook (K-step 32 == NUM_D -> one b/step)
// ---------------------------------------------------------------------------
__global__ __launch_bounds__(256) void gemm_xinput_kernel(
    const float* __restrict__ x, const int* __restrict__ fo,
    const int* __restrict__ cind, const float* __restrict__ cb,
    const short* __restrict__ WcT, float* __restrict__ xw)
{
    __shared__ short As[64 * 40];    // [row][k] pad 40 (80B = 20 banks)
    __shared__ short Bs[256 * 40];   // [col][k] pad 40

    const int tid  = threadIdx.x;
    const int w    = tid >> 6, l = tid & 63;
    const int row0 = blockIdx.x * 64;
    const int r    = tid >> 2, q = tid & 3;      // A staging: row r, k-quarter q
    const int grow = row0 + r;
    const int g16  = (l >> 4) * 8;               // k-offset (shorts) per lane group

    f32x4 acc[4][4] = {};

    for (int ks = 0; ks < 8; ++ks) {
        const int k0 = ks * 32;
        // --- stage A (64 x 32 bf16) ---
        float4 p0 = {0, 0, 0, 0}, p1 = {0, 0, 0, 0};
        if (grow < B_NODES) {
            const float4* src = (const float4*)(x + (size_t)grow * CIN + k0 + q * 8);
            p0 = src[0]; p1 = src[1];
        } else if (grow < NTOT) {
            int i = grow - B_NODES;
            int cidx = cind[ks * NUM_N + fo[i]];
            const float4* src = (const float4*)(cb +
                ((size_t)(ks * NUM_M + cidx)) * (2 * NUM_D) + q * 8);
            p0 = src[0]; p1 = src[1];
        }
        *(short8*)&As[r * 40 + q * 8] = pack2(p0, p1);

        // --- stage B (256 cols x 32 k bf16, from pre-transposed WcT) ---
        {
            const short8* wp = (const short8*)(WcT + (size_t)tid * 256 + k0);
            short8* bd = (short8*)&Bs[tid * 40];
            bd[0] = wp[0]; bd[1] = wp[1]; bd[2] = wp[2]; bd[3] = wp[3];
        }
        __syncthreads();

        short8 av[4], bv[4];
        #pragma unroll
        for (int m = 0; m < 4; ++m)
            av[m] = *(const short8*)&As[((l & 15) + 16 * m) * 40 + g16];
        #pragma unroll
        for (int n = 0; n < 4; ++n)
            bv[n] = *(const short8*)&Bs[((l & 15) + 16 * n + w * 64) * 40 + g16];
        #pragma unroll
        for (int m = 0; m < 4; ++m)
            #pragma unroll
            for (int n = 0; n < 4; ++n)
                acc[m][n] = __builtin_amdgcn_mfma_f32_16x16x32_bf16(
                    av[m], bv[n], acc[m][n], 0, 0, 0);
        __syncthreads();
    }

    // epilogue: C/D layout col=lane&15, row=(lane>>4)*4+j
    #pragma unroll
    for (int m = 0; m < 4; ++m) {
        int rbase = row0 + 16 * m + (l >> 4) * 4;
        #pragma unroll
        for (int n = 0; n < 4; ++n) {
            int col = w * 64 + 16 * n + (l & 15);
            #pragma unroll
            for (int j = 0; j < 4; ++j) {
                int rr = rbase + j;
                if (rr < NTOT) xw[(size_t)rr * COUT + col] = acc[m][n][j];
            }
        }
    }
}

// ---------------------------------------------------------------------------
// GEMM 2 (MFMA bf16, fused): out = xout[:B]@W_t + x@W_skip + (b_t+b_skip)
// virtual K = 512 (k<256: xout, k>=256: x); B from WoT [256][512]
// ---------------------------------------------------------------------------
__global__ __launch_bounds__(256) void gemm_out_kernel(
    const float* __restrict__ xout, const float* __restrict__ x,
    const short* __restrict__ WoT,
    const float* __restrict__ bt, const float* __restrict__ bskip,
    float* __restrict__ out)
{
    __shared__ short As[64 * 40];
    __shared__ short Bs[256 * 40];
    __shared__ float bsum[256];

    const int tid  = threadIdx.x;
    const int w    = tid >> 6, l = tid & 63;
    const int row0 = blockIdx.x * 64;
    const int r    = tid >> 2, q = tid & 3;
    const int grow = row0 + r;
    const int g16  = (l >> 4) * 8;

    bsum[tid] = bt[tid] + bskip[tid];

    f32x4 acc[4][4] = {};

    for (int ks = 0; ks < 16; ++ks) {
        const int k0 = ks * 32;
        float4 p0 = {0, 0, 0, 0}, p1 = {0, 0, 0, 0};
        if (grow < B_NODES) {
            int gk = k0 + q * 8;
            const float* base = (gk < 256)
                ? (xout + (size_t)grow * CIN + gk)
                : (x    + (size_t)grow * CIN + gk - 256);
            const float4* src = (const float4*)base;
            p0 = src[0]; p1 = src[1];
        }
        *(short8*)&As[r * 40 + q * 8] = pack2(p0, p1);

        {
            const short8* wp = (const short8*)(WoT + (size_t)tid * 512 + k0);
            short8* bd = (short8*)&Bs[tid * 40];
            bd[0] = wp[0]; bd[1] = wp[1]; bd[2] = wp[2]; bd[3] = wp[3];
        }
        __syncthreads();

        short8 av[4], bv[4];
        #pragma unroll
        for (int m = 0; m < 4; ++m)
            av[m] = *(const short8*)&As[((l & 15) + 16 * m) * 40 + g16];
        #pragma unroll
        for (int n = 0; n < 4; ++n)
            bv[n] = *(const short8*)&Bs[((l & 15) + 16 * n + w * 64) * 40 + g16];
        #pragma unroll
        for (int m = 0; m < 4; ++m)
            #pragma unroll
            for (int n = 0; n < 4; ++n)
                acc[m][n] = __builtin_amdgcn_mfma_f32_16x16x32_bf16(
                    av[m], bv[n], acc[m][n], 0, 0, 0);
        __syncthreads();
    }

    #pragma unroll
    for (int m = 0; m < 4; ++m) {
        int rbase = row0 + 16 * m + (l >> 4) * 4;
        #pragma unroll
        for (int n = 0; n < 4; ++n) {
            int col = w * 64 + 16 * n + (l & 15);
            float bc = bsum[col];
            #pragma unroll
            for (int j = 0; j < 4; ++j) {
                int rr = rbase + j;
                if (rr < B_NODES)
                    out[(size_t)rr * COUT + col] = acc[m][n][j] + bc;
            }
        }
    }
}

// ---------------------------------------------------------------------------
// CSR build step 1: histogram of destinations
// ---------------------------------------------------------------------------
__global__ __launch_bounds__(256) void hist_kernel(
    const int* __restrict__ ei, int* __restrict__ deg)
{
    for (int e = blockIdx.x * 256 + threadIdx.x; e < E_EDGES;
         e += gridDim.x * 256) {
        atomicAdd(&deg[ei[E_EDGES + e]], 1);
    }
}

// ---------------------------------------------------------------------------
// CSR build step 2: exclusive scan of deg -> offs
// ---------------------------------------------------------------------------
__global__ __launch_bounds__(1024) void scan_kernel(
    const int* __restrict__ deg, int* __restrict__ offs)
{
    __shared__ int part[1024];
    const int t = threadIdx.x;
    const int CH = 98;
    int lo = t * CH;
    int hi = lo + CH; if (hi > NTOT) hi = NTOT;
    int s = 0;
    for (int i = lo; i < hi && i < NTOT; ++i) s += deg[i];
    part[t] = s;
    __syncthreads();
    for (int st = 1; st < 1024; st <<= 1) {
        int v = (t >= st) ? part[t - st] : 0;
        __syncthreads();
        part[t] += v;
        __syncthreads();
    }
    int run = (t > 0) ? part[t - 1] : 0;
    for (int i = lo; i < hi && i < NTOT; ++i) {
        offs[i] = run;
        run += deg[i];
    }
    if (t == 1023) offs[NTOT] = part[1023];
}

// ---------------------------------------------------------------------------
// CSR build step 3: scatter edges into buckets
// ---------------------------------------------------------------------------
__global__ __launch_bounds__(256) void scatter_edges_kernel(
    const int* __restrict__ ei, const float* __restrict__ ew,
    const int* __restrict__ offs, int* __restrict__ deg,
    int* __restrict__ es, float* __restrict__ ewt)
{
    int e = blockIdx.x * 256 + threadIdx.x;
    if (e >= E_EDGES) return;
    int dst = ei[E_EDGES + e];
    int r = atomicSub(&deg[dst], 1);
    int pos = offs[dst] + r - 1;
    es[pos]  = ei[e];
    ewt[pos] = ew[e];
}

// ---------------------------------------------------------------------------
// gather-accumulate: one wave per destination node (+ fused info_backward)
// ---------------------------------------------------------------------------
__global__ __launch_bounds__(256) void gather_accum_kernel(
    const float* __restrict__ xw, const int* __restrict__ es,
    const float* __restrict__ ewt, const int* __restrict__ offs,
    const float* __restrict__ b_conv,
    const int* __restrict__ fo, const int* __restrict__ cind,
    const float* __restrict__ cb,
    float* __restrict__ xout, float* __restrict__ scalpart)
{
    const int wid  = threadIdx.x >> 6;
    const int lane = threadIdx.x & 63;
    const int node = blockIdx.x * 4 + wid;
    if (node >= NTOT) return;

    float4 acc = ((const float4*)b_conv)[lane];

    const int s = offs[node];
    const int e = offs[node + 1];
    for (int j = s; j < e; ++j) {
        int   src = es[j];
        float w   = ewt[j];
        float4 v = ((const float4*)(xw + (size_t)src * CIN))[lane];
        acc.x += v.x * w;
        acc.y += v.y * w;
        acc.z += v.z * w;
        acc.w += v.w * w;
    }

    if (node < B_NODES) {
        ((float4*)(xout + (size_t)node * CIN))[lane] = acc;
    } else {
        int i  = node - B_NODES;
        int c0 = lane * 4;
        int b  = c0 >> 5, d = c0 & 31;
        int cidx = cind[b * NUM_N + fo[i]];
        float4 g = *(const float4*)(cb +
            ((size_t)(b * NUM_M + cidx)) * (2 * NUM_D) + NUM_D + d);
        float v = acc.x * g.x + acc.y * g.y + acc.z * g.z + acc.w * g.w;
        #pragma unroll
        for (int off = 32; off > 0; off >>= 1) v += __shfl_down(v, off, 64);
        if (lane == 0)
            atomicAdd(&scalpart[(blockIdx.x * 4 + wid) & (NPART - 1)], v);
    }
}

// ---------------------------------------------------------------------------
// finalize: out_scalar = sum(scalpart) * warm_up_rate
// ---------------------------------------------------------------------------
__global__ __launch_bounds__(256) void finalize_kernel(
    const float* __restrict__ scalpart, const float* __restrict__ wur,
    float* __restrict__ out)
{
    __shared__ float wsum[4];
    float v = 0.0f;
    for (int i = threadIdx.x; i < NPART; i += 256) v += scalpart[i];
    #pragma unroll
    for (int off = 32; off > 0; off >>= 1) v += __shfl_down(v, off, 64);
    if ((threadIdx.x & 63) == 0) wsum[threadIdx.x >> 6] = v;
    __syncthreads();
    if (threadIdx.x == 0)
        out[(size_t)B_NODES * COUT] =
            (wsum[0] + wsum[1] + wsum[2] + wsum[3]) * wur[0];
}

// ---------------------------------------------------------------------------
extern "C" void kernel_launch(void* const* d_in, const int* in_sizes, int n_in,
                              void* d_out, int out_size, void* d_ws, size_t ws_size,
                              hipStream_t stream)
{
    const float* x       = (const float*)d_in[0];
    const float* ew      = (const float*)d_in[1];
    const float* cb      = (const float*)d_in[2];
    const float* W_conv  = (const float*)d_in[3];
    const float* b_conv  = (const float*)d_in[4];
    const float* W_t     = (const float*)d_in[5];
    const float* b_t     = (const float*)d_in[6];
    const float* W_skip  = (const float*)d_in[7];
    const float* b_skip  = (const float*)d_in[8];
    const float* wur     = (const float*)d_in[9];
    const int*   cind    = (const int*)d_in[10];
    const int*   fo      = (const int*)d_in[11];
    const int*   ei      = (const int*)d_in[12];

    float* out = (float*)d_out;

    // workspace layout (16B-aligned sections)
    float* xw       = (float*)d_ws;                       // NTOT*CIN
    float* xout     = xw + (size_t)NTOT * CIN;            // B_NODES*CIN
    float* ewt      = xout + (size_t)B_NODES * CIN;       // E
    float* scalpart = ewt + E_EDGES;                      // NPART
    short* WcT      = (short*)(scalpart + NPART);         // 256*256 bf16
    short* WoT      = WcT + 256 * 256;                    // 256*512 bf16
    int*   es       = (int*)(WoT + 256 * 512);            // E
    int*   deg      = es + E_EDGES;                       // NTOT
    int*   offs     = deg + NTOT;                         // NTOT+1

    hipMemsetAsync(deg, 0, sizeof(int) * NTOT, stream);
    hipMemsetAsync(scalpart, 0, sizeof(float) * NPART, stream);

    // weight transpose+convert (bf16, [n][k] layout)
    {
        dim3 g(4, 4);
        transpose_cvt_kernel<<<g, 256, 0, stream>>>(W_conv, WcT, 256, 0);
        transpose_cvt_kernel<<<g, 256, 0, stream>>>(W_t,    WoT, 512, 0);
        transpose_cvt_kernel<<<g, 256, 0, stream>>>(W_skip, WoT, 512, 256);
    }

    // CSR build
    hist_kernel<<<1024, 256, 0, stream>>>(ei, deg);
    scan_kernel<<<1, 1024, 0, stream>>>(deg, offs);
    scatter_edges_kernel<<<(E_EDGES + 255) / 256, 256, 0, stream>>>(
        ei, ew, offs, deg, es, ewt);

    // xw = x_input @ W_conv (MFMA, gather fused)
    gemm_xinput_kernel<<<(NTOT + 63) / 64, 256, 0, stream>>>(
        x, fo, cind, cb, WcT, xw);

    // per-destination gather + accumulate (+ fused info_backward)
    gather_accum_kernel<<<NTOT / 4, 256, 0, stream>>>(
        xw, es, ewt, offs, b_conv, fo, cind, cb, xout, scalpart);

    // out = xout[:B] @ W_t + x @ W_skip + biases (MFMA)
    gemm_out_kernel<<<(B_NODES + 63) / 64, 256, 0, stream>>>(
        xout, x, WoT, b_t, b_skip, out);

    finalize_kernel<<<1, 256, 0, stream>>>(scalpart, wur, out);
}

// Round 4
// 329.580 us; speedup vs baseline: 13.3034x; 1.4608x over previous
//
#include <hip/hip_runtime.h>

#define B_NODES 20000
#define N1_NODES 80000
#define NTOT 100000            // B + N1
#define E_EDGES 800000
#define CIN 256
#define COUT 256
#define NUM_D 32
#define NB 8                   // CIN / NUM_D
#define NUM_M 4096
#define NUM_N 200000
#define NPART 2048             // scalar partial buckets
#define NBLK 391               // ceil(NTOT/256)

typedef __attribute__((ext_vector_type(8))) short short8;
typedef __attribute__((ext_vector_type(4))) float f32x4;

// f32 -> bf16 round-to-nearest-even
__device__ inline unsigned short f2bf(float f) {
    unsigned int u = __float_as_uint(f);
    u += 0x7FFFu + ((u >> 16) & 1u);
    return (unsigned short)(u >> 16);
}

__device__ inline short8 pack2(float4 a, float4 b) {
    short8 r;
    r[0] = (short)f2bf(a.x); r[1] = (short)f2bf(a.y);
    r[2] = (short)f2bf(a.z); r[3] = (short)f2bf(a.w);
    r[4] = (short)f2bf(b.x); r[5] = (short)f2bf(b.y);
    r[6] = (short)f2bf(b.z); r[7] = (short)f2bf(b.w);
    return r;
}

// ---------------------------------------------------------------------------
// transpose + convert: dst[n][colOff + k] = bf16(src[k][n])
// ---------------------------------------------------------------------------
__global__ __launch_bounds__(256) void transpose_cvt_kernel(
    const float* __restrict__ src, short* __restrict__ dst,
    int dstStride, int colOff)
{
    __shared__ float Ls[64][65];
    const int k0 = blockIdx.x * 64, n0 = blockIdx.y * 64;
    const int tid = threadIdx.x;
    #pragma unroll
    for (int lp = 0; lp < 16; ++lp) {
        int idx = tid + lp * 256;
        int rr = idx >> 6, cc = idx & 63;
        Ls[rr][cc] = src[(size_t)(k0 + rr) * 256 + n0 + cc];
    }
    __syncthreads();
    #pragma unroll
    for (int lp = 0; lp < 16; ++lp) {
        int idx = tid + lp * 256;
        int rr = idx >> 6, cc = idx & 63;
        dst[(size_t)(n0 + rr) * dstStride + colOff + k0 + cc] =
            (short)f2bf(Ls[cc][rr]);
    }
}

// ---------------------------------------------------------------------------
// GEMM 1 (MFMA bf16): xw = x_input @ W_conv
// ---------------------------------------------------------------------------
__global__ __launch_bounds__(256) void gemm_xinput_kernel(
    const float* __restrict__ x, const int* __restrict__ fo,
    const int* __restrict__ cind, const float* __restrict__ cb,
    const short* __restrict__ WcT, float* __restrict__ xw)
{
    __shared__ short As[64 * 40];
    __shared__ short Bs[256 * 40];

    const int tid  = threadIdx.x;
    const int w    = tid >> 6, l = tid & 63;
    const int row0 = blockIdx.x * 64;
    const int r    = tid >> 2, q = tid & 3;
    const int grow = row0 + r;
    const int g16  = (l >> 4) * 8;

    f32x4 acc[4][4] = {};

    for (int ks = 0; ks < 8; ++ks) {
        const int k0 = ks * 32;
        float4 p0 = {0, 0, 0, 0}, p1 = {0, 0, 0, 0};
        if (grow < B_NODES) {
            const float4* src = (const float4*)(x + (size_t)grow * CIN + k0 + q * 8);
            p0 = src[0]; p1 = src[1];
        } else if (grow < NTOT) {
            int i = grow - B_NODES;
            int cidx = cind[ks * NUM_N + fo[i]];
            const float4* src = (const float4*)(cb +
                ((size_t)(ks * NUM_M + cidx)) * (2 * NUM_D) + q * 8);
            p0 = src[0]; p1 = src[1];
        }
        *(short8*)&As[r * 40 + q * 8] = pack2(p0, p1);

        {
            const short8* wp = (const short8*)(WcT + (size_t)tid * 256 + k0);
            short8* bd = (short8*)&Bs[tid * 40];
            bd[0] = wp[0]; bd[1] = wp[1]; bd[2] = wp[2]; bd[3] = wp[3];
        }
        __syncthreads();

        short8 av[4], bv[4];
        #pragma unroll
        for (int m = 0; m < 4; ++m)
            av[m] = *(const short8*)&As[((l & 15) + 16 * m) * 40 + g16];
        #pragma unroll
        for (int n = 0; n < 4; ++n)
            bv[n] = *(const short8*)&Bs[((l & 15) + 16 * n + w * 64) * 40 + g16];
        #pragma unroll
        for (int m = 0; m < 4; ++m)
            #pragma unroll
            for (int n = 0; n < 4; ++n)
                acc[m][n] = __builtin_amdgcn_mfma_f32_16x16x32_bf16(
                    av[m], bv[n], acc[m][n], 0, 0, 0);
        __syncthreads();
    }

    #pragma unroll
    for (int m = 0; m < 4; ++m) {
        int rbase = row0 + 16 * m + (l >> 4) * 4;
        #pragma unroll
        for (int n = 0; n < 4; ++n) {
            int col = w * 64 + 16 * n + (l & 15);
            #pragma unroll
            for (int j = 0; j < 4; ++j) {
                int rr = rbase + j;
                if (rr < NTOT) xw[(size_t)rr * COUT + col] = acc[m][n][j];
            }
        }
    }
}

// ---------------------------------------------------------------------------
// GEMM 2 (MFMA bf16, fused): out = xout[:B]@W_t + x@W_skip + (b_t+b_skip)
// ---------------------------------------------------------------------------
__global__ __launch_bounds__(256) void gemm_out_kernel(
    const float* __restrict__ xout, const float* __restrict__ x,
    const short* __restrict__ WoT,
    const float* __restrict__ bt, const float* __restrict__ bskip,
    float* __restrict__ out)
{
    __shared__ short As[64 * 40];
    __shared__ short Bs[256 * 40];
    __shared__ float bsum[256];

    const int tid  = threadIdx.x;
    const int w    = tid >> 6, l = tid & 63;
    const int row0 = blockIdx.x * 64;
    const int r    = tid >> 2, q = tid & 3;
    const int grow = row0 + r;
    const int g16  = (l >> 4) * 8;

    bsum[tid] = bt[tid] + bskip[tid];

    f32x4 acc[4][4] = {};

    for (int ks = 0; ks < 16; ++ks) {
        const int k0 = ks * 32;
        float4 p0 = {0, 0, 0, 0}, p1 = {0, 0, 0, 0};
        if (grow < B_NODES) {
            int gk = k0 + q * 8;
            const float* base = (gk < 256)
                ? (xout + (size_t)grow * CIN + gk)
                : (x    + (size_t)grow * CIN + gk - 256);
            const float4* src = (const float4*)base;
            p0 = src[0]; p1 = src[1];
        }
        *(short8*)&As[r * 40 + q * 8] = pack2(p0, p1);

        {
            const short8* wp = (const short8*)(WoT + (size_t)tid * 512 + k0);
            short8* bd = (short8*)&Bs[tid * 40];
            bd[0] = wp[0]; bd[1] = wp[1]; bd[2] = wp[2]; bd[3] = wp[3];
        }
        __syncthreads();

        short8 av[4], bv[4];
        #pragma unroll
        for (int m = 0; m < 4; ++m)
            av[m] = *(const short8*)&As[((l & 15) + 16 * m) * 40 + g16];
        #pragma unroll
        for (int n = 0; n < 4; ++n)
            bv[n] = *(const short8*)&Bs[((l & 15) + 16 * n + w * 64) * 40 + g16];
        #pragma unroll
        for (int m = 0; m < 4; ++m)
            #pragma unroll
            for (int n = 0; n < 4; ++n)
                acc[m][n] = __builtin_amdgcn_mfma_f32_16x16x32_bf16(
                    av[m], bv[n], acc[m][n], 0, 0, 0);
        __syncthreads();
    }

    #pragma unroll
    for (int m = 0; m < 4; ++m) {
        int rbase = row0 + 16 * m + (l >> 4) * 4;
        #pragma unroll
        for (int n = 0; n < 4; ++n) {
            int col = w * 64 + 16 * n + (l & 15);
            float bc = bsum[col];
            #pragma unroll
            for (int j = 0; j < 4; ++j) {
                int rr = rbase + j;
                if (rr < B_NODES)
                    out[(size_t)rr * COUT + col] = acc[m][n][j] + bc;
            }
        }
    }
}

// ---------------------------------------------------------------------------
// CSR build step 1: histogram of destinations
// ---------------------------------------------------------------------------
__global__ __launch_bounds__(256) void hist_kernel(
    const int* __restrict__ ei, int* __restrict__ deg)
{
    for (int e = blockIdx.x * 256 + threadIdx.x; e < E_EDGES;
         e += gridDim.x * 256) {
        atomicAdd(&deg[ei[E_EDGES + e]], 1);
    }
}

// ---------------------------------------------------------------------------
// scan step A: per-256-chunk block sums (coalesced)
// ---------------------------------------------------------------------------
__global__ __launch_bounds__(256) void scan_blocksum_kernel(
    const int* __restrict__ deg, int* __restrict__ blocksum)
{
    const int t = threadIdx.x;
    int i = blockIdx.x * 256 + t;
    int v = (i < NTOT) ? deg[i] : 0;
    #pragma unroll
    for (int off = 32; off > 0; off >>= 1) v += __shfl_down(v, off, 64);
    __shared__ int ws[4];
    if ((t & 63) == 0) ws[t >> 6] = v;
    __syncthreads();
    if (t == 0) blocksum[blockIdx.x] = ws[0] + ws[1] + ws[2] + ws[3];
}

// ---------------------------------------------------------------------------
// scan step B: single-block scan of NBLK partials -> blockpre (exclusive),
// offs[NTOT] = total
// ---------------------------------------------------------------------------
__global__ __launch_bounds__(512) void scan_partials_kernel(
    const int* __restrict__ blocksum, int* __restrict__ blockpre,
    int* __restrict__ offs)
{
    __shared__ int part[512];
    const int t = threadIdx.x;
    part[t] = (t < NBLK) ? blocksum[t] : 0;
    __syncthreads();
    #pragma unroll
    for (int st = 1; st < 512; st <<= 1) {
        int v = (t >= st) ? part[t - st] : 0;
        __syncthreads();
        part[t] += v;
        __syncthreads();
    }
    if (t < NBLK) blockpre[t] = (t > 0) ? part[t - 1] : 0;
    if (t == 511) offs[NTOT] = part[511];
}

// ---------------------------------------------------------------------------
// scan step C: local block scan + add block prefix -> offs (exclusive)
// ---------------------------------------------------------------------------
__global__ __launch_bounds__(256) void scan_final_kernel(
    const int* __restrict__ deg, const int* __restrict__ blockpre,
    int* __restrict__ offs)
{
    __shared__ int part[256];
    const int t = threadIdx.x;
    int i = blockIdx.x * 256 + t;
    int d = (i < NTOT) ? deg[i] : 0;
    part[t] = d;
    __syncthreads();
    #pragma unroll
    for (int st = 1; st < 256; st <<= 1) {
        int v = (t >= st) ? part[t - st] : 0;
        __syncthreads();
        part[t] += v;
        __syncthreads();
    }
    if (i < NTOT) offs[i] = blockpre[blockIdx.x] + part[t] - d;
}

// ---------------------------------------------------------------------------
// CSR build step 3: scatter edges into buckets
// ---------------------------------------------------------------------------
__global__ __launch_bounds__(256) void scatter_edges_kernel(
    const int* __restrict__ ei, const float* __restrict__ ew,
    const int* __restrict__ offs, int* __restrict__ deg,
    int* __restrict__ es, float* __restrict__ ewt)
{
    int e = blockIdx.x * 256 + threadIdx.x;
    if (e >= E_EDGES) return;
    int dst = ei[E_EDGES + e];
    int r = atomicSub(&deg[dst], 1);
    int pos = offs[dst] + r - 1;
    es[pos]  = ei[e];
    ewt[pos] = ew[e];
}

// ---------------------------------------------------------------------------
// gather-accumulate: one wave per destination node (+ fused info_backward)
// unroll x4 on the edge loop for memory-level parallelism
// ---------------------------------------------------------------------------
__global__ __launch_bounds__(256) void gather_accum_kernel(
    const float* __restrict__ xw, const int* __restrict__ es,
    const float* __restrict__ ewt, const int* __restrict__ offs,
    const float* __restrict__ b_conv,
    const int* __restrict__ fo, const int* __restrict__ cind,
    const float* __restrict__ cb,
    float* __restrict__ xout, float* __restrict__ scalpart)
{
    const int wid  = threadIdx.x >> 6;
    const int lane = threadIdx.x & 63;
    const int node = blockIdx.x * 4 + wid;
    if (node >= NTOT) return;

    float4 acc = ((const float4*)b_conv)[lane];

    const int s = offs[node];
    const int e = offs[node + 1];
    int j = s;
    for (; j + 4 <= e; j += 4) {
        int   s0 = es[j],     s1 = es[j + 1],  s2 = es[j + 2],  s3 = es[j + 3];
        float w0 = ewt[j],    w1 = ewt[j + 1], w2 = ewt[j + 2], w3 = ewt[j + 3];
        float4 v0 = ((const float4*)(xw + (size_t)s0 * CIN))[lane];
        float4 v1 = ((const float4*)(xw + (size_t)s1 * CIN))[lane];
        float4 v2 = ((const float4*)(xw + (size_t)s2 * CIN))[lane];
        float4 v3 = ((const float4*)(xw + (size_t)s3 * CIN))[lane];
        acc.x += v0.x * w0 + v1.x * w1 + v2.x * w2 + v3.x * w3;
        acc.y += v0.y * w0 + v1.y * w1 + v2.y * w2 + v3.y * w3;
        acc.z += v0.z * w0 + v1.z * w1 + v2.z * w2 + v3.z * w3;
        acc.w += v0.w * w0 + v1.w * w1 + v2.w * w2 + v3.w * w3;
    }
    for (; j < e; ++j) {
        int   src = es[j];
        float w   = ewt[j];
        float4 v = ((const float4*)(xw + (size_t)src * CIN))[lane];
        acc.x += v.x * w;
        acc.y += v.y * w;
        acc.z += v.z * w;
        acc.w += v.w * w;
    }

    if (node < B_NODES) {
        ((float4*)(xout + (size_t)node * CIN))[lane] = acc;
    } else {
        int i  = node - B_NODES;
        int c0 = lane * 4;
        int b  = c0 >> 5, d = c0 & 31;
        int cidx = cind[b * NUM_N + fo[i]];
        float4 g = *(const float4*)(cb +
            ((size_t)(b * NUM_M + cidx)) * (2 * NUM_D) + NUM_D + d);
        float v = acc.x * g.x + acc.y * g.y + acc.z * g.z + acc.w * g.w;
        #pragma unroll
        for (int off = 32; off > 0; off >>= 1) v += __shfl_down(v, off, 64);
        if (lane == 0)
            atomicAdd(&scalpart[(blockIdx.x * 4 + wid) & (NPART - 1)], v);
    }
}

// ---------------------------------------------------------------------------
// finalize: out_scalar = sum(scalpart) * warm_up_rate
// ---------------------------------------------------------------------------
__global__ __launch_bounds__(256) void finalize_kernel(
    const float* __restrict__ scalpart, const float* __restrict__ wur,
    float* __restrict__ out)
{
    __shared__ float wsum[4];
    float v = 0.0f;
    for (int i = threadIdx.x; i < NPART; i += 256) v += scalpart[i];
    #pragma unroll
    for (int off = 32; off > 0; off >>= 1) v += __shfl_down(v, off, 64);
    if ((threadIdx.x & 63) == 0) wsum[threadIdx.x >> 6] = v;
    __syncthreads();
    if (threadIdx.x == 0)
        out[(size_t)B_NODES * COUT] =
            (wsum[0] + wsum[1] + wsum[2] + wsum[3]) * wur[0];
}

// ---------------------------------------------------------------------------
extern "C" void kernel_launch(void* const* d_in, const int* in_sizes, int n_in,
                              void* d_out, int out_size, void* d_ws, size_t ws_size,
                              hipStream_t stream)
{
    const float* x       = (const float*)d_in[0];
    const float* ew      = (const float*)d_in[1];
    const float* cb      = (const float*)d_in[2];
    const float* W_conv  = (const float*)d_in[3];
    const float* b_conv  = (const float*)d_in[4];
    const float* W_t     = (const float*)d_in[5];
    const float* b_t     = (const float*)d_in[6];
    const float* W_skip  = (const float*)d_in[7];
    const float* b_skip  = (const float*)d_in[8];
    const float* wur     = (const float*)d_in[9];
    const int*   cind    = (const int*)d_in[10];
    const int*   fo      = (const int*)d_in[11];
    const int*   ei      = (const int*)d_in[12];

    float* out = (float*)d_out;

    // workspace layout (16B-aligned sections)
    float* xw       = (float*)d_ws;                       // NTOT*CIN
    float* xout     = xw + (size_t)NTOT * CIN;            // B_NODES*CIN
    float* ewt      = xout + (size_t)B_NODES * CIN;       // E
    float* scalpart = ewt + E_EDGES;                      // NPART
    short* WcT      = (short*)(scalpart + NPART);         // 256*256 bf16
    short* WoT      = WcT + 256 * 256;                    // 256*512 bf16
    int*   es       = (int*)(WoT + 256 * 512);            // E
    int*   deg      = es + E_EDGES;                       // NTOT
    int*   offs     = deg + NTOT;                         // NTOT+1
    int*   blocksum = offs + NTOT + 1;                    // NBLK
    int*   blockpre = blocksum + NBLK;                    // NBLK

    hipMemsetAsync(deg, 0, sizeof(int) * NTOT, stream);
    hipMemsetAsync(scalpart, 0, sizeof(float) * NPART, stream);

    // weight transpose+convert (bf16, [n][k] layout)
    {
        dim3 g(4, 4);
        transpose_cvt_kernel<<<g, 256, 0, stream>>>(W_conv, WcT, 256, 0);
        transpose_cvt_kernel<<<g, 256, 0, stream>>>(W_t,    WoT, 512, 0);
        transpose_cvt_kernel<<<g, 256, 0, stream>>>(W_skip, WoT, 512, 256);
    }

    // CSR build
    hist_kernel<<<1024, 256, 0, stream>>>(ei, deg);
    scan_blocksum_kernel<<<NBLK, 256, 0, stream>>>(deg, blocksum);
    scan_partials_kernel<<<1, 512, 0, stream>>>(blocksum, blockpre, offs);
    scan_final_kernel<<<NBLK, 256, 0, stream>>>(deg, blockpre, offs);
    scatter_edges_kernel<<<(E_EDGES + 255) / 256, 256, 0, stream>>>(
        ei, ew, offs, deg, es, ewt);

    // xw = x_input @ W_conv (MFMA, gather fused)
    gemm_xinput_kernel<<<(NTOT + 63) / 64, 256, 0, stream>>>(
        x, fo, cind, cb, WcT, xw);

    // per-destination gather + accumulate (+ fused info_backward)
    gather_accum_kernel<<<NTOT / 4, 256, 0, stream>>>(
        xw, es, ewt, offs, b_conv, fo, cind, cb, xout, scalpart);

    // out = xout[:B] @ W_t + x @ W_skip + biases (MFMA)
    gemm_out_kernel<<<(B_NODES + 63) / 64, 256, 0, stream>>>(
        xout, x, WoT, b_t, b_skip, out);

    finalize_kernel<<<1, 256, 0, stream>>>(scalpart, wur, out);
}

// Round 5
// 268.640 us; speedup vs baseline: 16.3213x; 1.2268x over previous
//
#include <hip/hip_runtime.h>

#define B_NODES 20000
#define N1_NODES 80000
#define NTOT 100000            // B + N1
#define E_EDGES 800000
#define CIN 256
#define COUT 256
#define NUM_D 32
#define NB 8                   // CIN / NUM_D
#define NUM_M 4096
#define NUM_N 200000
#define NPART 2048             // scalar partial buckets
#define NBLK 391               // ceil(NTOT/256)

typedef __attribute__((ext_vector_type(8))) short short8;
typedef __attribute__((ext_vector_type(4))) float f32x4;
typedef __attribute__((ext_vector_type(4))) unsigned short u16x4;

// f32 -> bf16 round-to-nearest-even
__device__ inline unsigned short f2bf(float f) {
    unsigned int u = __float_as_uint(f);
    u += 0x7FFFu + ((u >> 16) & 1u);
    return (unsigned short)(u >> 16);
}
__device__ inline float bf2f(unsigned short u) {
    return __uint_as_float((unsigned int)u << 16);
}

__device__ inline short8 pack2(float4 a, float4 b) {
    short8 r;
    r[0] = (short)f2bf(a.x); r[1] = (short)f2bf(a.y);
    r[2] = (short)f2bf(a.z); r[3] = (short)f2bf(a.w);
    r[4] = (short)f2bf(b.x); r[5] = (short)f2bf(b.y);
    r[6] = (short)f2bf(b.z); r[7] = (short)f2bf(b.w);
    return r;
}

// ---------------------------------------------------------------------------
// transpose + convert: dst[n][colOff + k] = bf16(src[k][n])
// ---------------------------------------------------------------------------
__global__ __launch_bounds__(256) void transpose_cvt_kernel(
    const float* __restrict__ src, short* __restrict__ dst,
    int dstStride, int colOff)
{
    __shared__ float Ls[64][65];
    const int k0 = blockIdx.x * 64, n0 = blockIdx.y * 64;
    const int tid = threadIdx.x;
    #pragma unroll
    for (int lp = 0; lp < 16; ++lp) {
        int idx = tid + lp * 256;
        int rr = idx >> 6, cc = idx & 63;
        Ls[rr][cc] = src[(size_t)(k0 + rr) * 256 + n0 + cc];
    }
    __syncthreads();
    #pragma unroll
    for (int lp = 0; lp < 16; ++lp) {
        int idx = tid + lp * 256;
        int rr = idx >> 6, cc = idx & 63;
        dst[(size_t)(n0 + rr) * dstStride + colOff + k0 + cc] =
            (short)f2bf(Ls[cc][rr]);
    }
}

// ---------------------------------------------------------------------------
// GEMM 1 (MFMA bf16): xw = x_input @ W_conv   (xw stored as bf16)
// ---------------------------------------------------------------------------
__global__ __launch_bounds__(256) void gemm_xinput_kernel(
    const float* __restrict__ x, const int* __restrict__ fo,
    const int* __restrict__ cind, const float* __restrict__ cb,
    const short* __restrict__ WcT, unsigned short* __restrict__ xwb)
{
    __shared__ short As[64 * 40];
    __shared__ short Bs[256 * 40];

    const int tid  = threadIdx.x;
    const int w    = tid >> 6, l = tid & 63;
    const int row0 = blockIdx.x * 64;
    const int r    = tid >> 2, q = tid & 3;
    const int grow = row0 + r;
    const int g16  = (l >> 4) * 8;

    f32x4 acc[4][4] = {};

    for (int ks = 0; ks < 8; ++ks) {
        const int k0 = ks * 32;
        float4 p0 = {0, 0, 0, 0}, p1 = {0, 0, 0, 0};
        if (grow < B_NODES) {
            const float4* src = (const float4*)(x + (size_t)grow * CIN + k0 + q * 8);
            p0 = src[0]; p1 = src[1];
        } else if (grow < NTOT) {
            int i = grow - B_NODES;
            int cidx = cind[ks * NUM_N + fo[i]];
            const float4* src = (const float4*)(cb +
                ((size_t)(ks * NUM_M + cidx)) * (2 * NUM_D) + q * 8);
            p0 = src[0]; p1 = src[1];
        }
        *(short8*)&As[r * 40 + q * 8] = pack2(p0, p1);

        {
            const short8* wp = (const short8*)(WcT + (size_t)tid * 256 + k0);
            short8* bd = (short8*)&Bs[tid * 40];
            bd[0] = wp[0]; bd[1] = wp[1]; bd[2] = wp[2]; bd[3] = wp[3];
        }
        __syncthreads();

        short8 av[4], bv[4];
        #pragma unroll
        for (int m = 0; m < 4; ++m)
            av[m] = *(const short8*)&As[((l & 15) + 16 * m) * 40 + g16];
        #pragma unroll
        for (int n = 0; n < 4; ++n)
            bv[n] = *(const short8*)&Bs[((l & 15) + 16 * n + w * 64) * 40 + g16];
        #pragma unroll
        for (int m = 0; m < 4; ++m)
            #pragma unroll
            for (int n = 0; n < 4; ++n)
                acc[m][n] = __builtin_amdgcn_mfma_f32_16x16x32_bf16(
                    av[m], bv[n], acc[m][n], 0, 0, 0);
        __syncthreads();
    }

    #pragma unroll
    for (int m = 0; m < 4; ++m) {
        int rbase = row0 + 16 * m + (l >> 4) * 4;
        #pragma unroll
        for (int n = 0; n < 4; ++n) {
            int col = w * 64 + 16 * n + (l & 15);
            #pragma unroll
            for (int j = 0; j < 4; ++j) {
                int rr = rbase + j;
                if (rr < NTOT)
                    xwb[(size_t)rr * COUT + col] = f2bf(acc[m][n][j]);
            }
        }
    }
}

// ---------------------------------------------------------------------------
// GEMM 2 (MFMA bf16, fused): out = xout[:B]@W_t + x@W_skip + (b_t+b_skip)
// ---------------------------------------------------------------------------
__global__ __launch_bounds__(256) void gemm_out_kernel(
    const float* __restrict__ xout, const float* __restrict__ x,
    const short* __restrict__ WoT,
    const float* __restrict__ bt, const float* __restrict__ bskip,
    float* __restrict__ out)
{
    __shared__ short As[64 * 40];
    __shared__ short Bs[256 * 40];
    __shared__ float bsum[256];

    const int tid  = threadIdx.x;
    const int w    = tid >> 6, l = tid & 63;
    const int row0 = blockIdx.x * 64;
    const int r    = tid >> 2, q = tid & 3;
    const int grow = row0 + r;
    const int g16  = (l >> 4) * 8;

    bsum[tid] = bt[tid] + bskip[tid];

    f32x4 acc[4][4] = {};

    for (int ks = 0; ks < 16; ++ks) {
        const int k0 = ks * 32;
        float4 p0 = {0, 0, 0, 0}, p1 = {0, 0, 0, 0};
        if (grow < B_NODES) {
            int gk = k0 + q * 8;
            const float* base = (gk < 256)
                ? (xout + (size_t)grow * CIN + gk)
                : (x    + (size_t)grow * CIN + gk - 256);
            const float4* src = (const float4*)base;
            p0 = src[0]; p1 = src[1];
        }
        *(short8*)&As[r * 40 + q * 8] = pack2(p0, p1);

        {
            const short8* wp = (const short8*)(WoT + (size_t)tid * 512 + k0);
            short8* bd = (short8*)&Bs[tid * 40];
            bd[0] = wp[0]; bd[1] = wp[1]; bd[2] = wp[2]; bd[3] = wp[3];
        }
        __syncthreads();

        short8 av[4], bv[4];
        #pragma unroll
        for (int m = 0; m < 4; ++m)
            av[m] = *(const short8*)&As[((l & 15) + 16 * m) * 40 + g16];
        #pragma unroll
        for (int n = 0; n < 4; ++n)
            bv[n] = *(const short8*)&Bs[((l & 15) + 16 * n + w * 64) * 40 + g16];
        #pragma unroll
        for (int m = 0; m < 4; ++m)
            #pragma unroll
            for (int n = 0; n < 4; ++n)
                acc[m][n] = __builtin_amdgcn_mfma_f32_16x16x32_bf16(
                    av[m], bv[n], acc[m][n], 0, 0, 0);
        __syncthreads();
    }

    #pragma unroll
    for (int m = 0; m < 4; ++m) {
        int rbase = row0 + 16 * m + (l >> 4) * 4;
        #pragma unroll
        for (int n = 0; n < 4; ++n) {
            int col = w * 64 + 16 * n + (l & 15);
            float bc = bsum[col];
            #pragma unroll
            for (int j = 0; j < 4; ++j) {
                int rr = rbase + j;
                if (rr < B_NODES)
                    out[(size_t)rr * COUT + col] = acc[m][n][j] + bc;
            }
        }
    }
}

// ---------------------------------------------------------------------------
// CSR build step 1: histogram of destinations
// ---------------------------------------------------------------------------
__global__ __launch_bounds__(256) void hist_kernel(
    const int* __restrict__ ei, int* __restrict__ deg)
{
    for (int e = blockIdx.x * 256 + threadIdx.x; e < E_EDGES;
         e += gridDim.x * 256) {
        atomicAdd(&deg[ei[E_EDGES + e]], 1);
    }
}

// ---------------------------------------------------------------------------
// scan step A: per-256-chunk block sums (coalesced)
// ---------------------------------------------------------------------------
__global__ __launch_bounds__(256) void scan_blocksum_kernel(
    const int* __restrict__ deg, int* __restrict__ blocksum)
{
    const int t = threadIdx.x;
    int i = blockIdx.x * 256 + t;
    int v = (i < NTOT) ? deg[i] : 0;
    #pragma unroll
    for (int off = 32; off > 0; off >>= 1) v += __shfl_down(v, off, 64);
    __shared__ int ws[4];
    if ((t & 63) == 0) ws[t >> 6] = v;
    __syncthreads();
    if (t == 0) blocksum[blockIdx.x] = ws[0] + ws[1] + ws[2] + ws[3];
}

// ---------------------------------------------------------------------------
// scan step B: single-block scan of NBLK partials -> blockpre (exclusive),
// offs[NTOT] = total
// ---------------------------------------------------------------------------
__global__ __launch_bounds__(512) void scan_partials_kernel(
    const int* __restrict__ blocksum, int* __restrict__ blockpre,
    int* __restrict__ offs)
{
    __shared__ int part[512];
    const int t = threadIdx.x;
    part[t] = (t < NBLK) ? blocksum[t] : 0;
    __syncthreads();
    #pragma unroll
    for (int st = 1; st < 512; st <<= 1) {
        int v = (t >= st) ? part[t - st] : 0;
        __syncthreads();
        part[t] += v;
        __syncthreads();
    }
    if (t < NBLK) blockpre[t] = (t > 0) ? part[t - 1] : 0;
    if (t == 511) offs[NTOT] = part[511];
}

// ---------------------------------------------------------------------------
// scan step C: local block scan + add block prefix -> offs (exclusive)
// ---------------------------------------------------------------------------
__global__ __launch_bounds__(256) void scan_final_kernel(
    const int* __restrict__ deg, const int* __restrict__ blockpre,
    int* __restrict__ offs)
{
    __shared__ int part[256];
    const int t = threadIdx.x;
    int i = blockIdx.x * 256 + t;
    int d = (i < NTOT) ? deg[i] : 0;
    part[t] = d;
    __syncthreads();
    #pragma unroll
    for (int st = 1; st < 256; st <<= 1) {
        int v = (t >= st) ? part[t - st] : 0;
        __syncthreads();
        part[t] += v;
        __syncthreads();
    }
    if (i < NTOT) offs[i] = blockpre[blockIdx.x] + part[t] - d;
}

// ---------------------------------------------------------------------------
// CSR build step 3: scatter edges into buckets
// ---------------------------------------------------------------------------
__global__ __launch_bounds__(256) void scatter_edges_kernel(
    const int* __restrict__ ei, const float* __restrict__ ew,
    const int* __restrict__ offs, int* __restrict__ deg,
    int* __restrict__ es, float* __restrict__ ewt)
{
    int e = blockIdx.x * 256 + threadIdx.x;
    if (e >= E_EDGES) return;
    int dst = ei[E_EDGES + e];
    int r = atomicSub(&deg[dst], 1);
    int pos = offs[dst] + r - 1;
    es[pos]  = ei[e];
    ewt[pos] = ew[e];
}

// ---------------------------------------------------------------------------
// gather-accumulate: one wave per destination node (+ fused info_backward)
// xw rows are bf16 (512 B) -> lane reads ushort4 (8 B), converts, f32 FMA
// ---------------------------------------------------------------------------
__global__ __launch_bounds__(256) void gather_accum_kernel(
    const unsigned short* __restrict__ xwb, const int* __restrict__ es,
    const float* __restrict__ ewt, const int* __restrict__ offs,
    const float* __restrict__ b_conv,
    const int* __restrict__ fo, const int* __restrict__ cind,
    const float* __restrict__ cb,
    float* __restrict__ xout, float* __restrict__ scalpart)
{
    const int wid  = threadIdx.x >> 6;
    const int lane = threadIdx.x & 63;
    const int node = blockIdx.x * 4 + wid;
    if (node >= NTOT) return;

    float4 acc = ((const float4*)b_conv)[lane];

    const int s = offs[node];
    const int e = offs[node + 1];
    int j = s;
    for (; j + 4 <= e; j += 4) {
        int   s0 = es[j],     s1 = es[j + 1],  s2 = es[j + 2],  s3 = es[j + 3];
        float w0 = ewt[j],    w1 = ewt[j + 1], w2 = ewt[j + 2], w3 = ewt[j + 3];
        u16x4 u0 = ((const u16x4*)(xwb + (size_t)s0 * CIN))[lane];
        u16x4 u1 = ((const u16x4*)(xwb + (size_t)s1 * CIN))[lane];
        u16x4 u2 = ((const u16x4*)(xwb + (size_t)s2 * CIN))[lane];
        u16x4 u3 = ((const u16x4*)(xwb + (size_t)s3 * CIN))[lane];
        acc.x += bf2f(u0[0]) * w0 + bf2f(u1[0]) * w1 + bf2f(u2[0]) * w2 + bf2f(u3[0]) * w3;
        acc.y += bf2f(u0[1]) * w0 + bf2f(u1[1]) * w1 + bf2f(u2[1]) * w2 + bf2f(u3[1]) * w3;
        acc.z += bf2f(u0[2]) * w0 + bf2f(u1[2]) * w1 + bf2f(u2[2]) * w2 + bf2f(u3[2]) * w3;
        acc.w += bf2f(u0[3]) * w0 + bf2f(u1[3]) * w1 + bf2f(u2[3]) * w2 + bf2f(u3[3]) * w3;
    }
    for (; j < e; ++j) {
        int   src = es[j];
        float w   = ewt[j];
        u16x4 u = ((const u16x4*)(xwb + (size_t)src * CIN))[lane];
        acc.x += bf2f(u[0]) * w;
        acc.y += bf2f(u[1]) * w;
        acc.z += bf2f(u[2]) * w;
        acc.w += bf2f(u[3]) * w;
    }

    if (node < B_NODES) {
        ((float4*)(xout + (size_t)node * CIN))[lane] = acc;
    } else {
        int i  = node - B_NODES;
        int c0 = lane * 4;
        int b  = c0 >> 5, d = c0 & 31;
        int cidx = cind[b * NUM_N + fo[i]];
        float4 g = *(const float4*)(cb +
            ((size_t)(b * NUM_M + cidx)) * (2 * NUM_D) + NUM_D + d);
        float v = acc.x * g.x + acc.y * g.y + acc.z * g.z + acc.w * g.w;
        #pragma unroll
        for (int off = 32; off > 0; off >>= 1) v += __shfl_down(v, off, 64);
        if (lane == 0)
            atomicAdd(&scalpart[(blockIdx.x * 4 + wid) & (NPART - 1)], v);
    }
}

// ---------------------------------------------------------------------------
// finalize: out_scalar = sum(scalpart) * warm_up_rate
// ---------------------------------------------------------------------------
__global__ __launch_bounds__(256) void finalize_kernel(
    const float* __restrict__ scalpart, const float* __restrict__ wur,
    float* __restrict__ out)
{
    __shared__ float wsum[4];
    float v = 0.0f;
    for (int i = threadIdx.x; i < NPART; i += 256) v += scalpart[i];
    #pragma unroll
    for (int off = 32; off > 0; off >>= 1) v += __shfl_down(v, off, 64);
    if ((threadIdx.x & 63) == 0) wsum[threadIdx.x >> 6] = v;
    __syncthreads();
    if (threadIdx.x == 0)
        out[(size_t)B_NODES * COUT] =
            (wsum[0] + wsum[1] + wsum[2] + wsum[3]) * wur[0];
}

// ---------------------------------------------------------------------------
extern "C" void kernel_launch(void* const* d_in, const int* in_sizes, int n_in,
                              void* d_out, int out_size, void* d_ws, size_t ws_size,
                              hipStream_t stream)
{
    const float* x       = (const float*)d_in[0];
    const float* ew      = (const float*)d_in[1];
    const float* cb      = (const float*)d_in[2];
    const float* W_conv  = (const float*)d_in[3];
    const float* b_conv  = (const float*)d_in[4];
    const float* W_t     = (const float*)d_in[5];
    const float* b_t     = (const float*)d_in[6];
    const float* W_skip  = (const float*)d_in[7];
    const float* b_skip  = (const float*)d_in[8];
    const float* wur     = (const float*)d_in[9];
    const int*   cind    = (const int*)d_in[10];
    const int*   fo      = (const int*)d_in[11];
    const int*   ei      = (const int*)d_in[12];

    float* out = (float*)d_out;

    // workspace layout (16B-aligned sections)
    unsigned short* xwb = (unsigned short*)d_ws;          // NTOT*CIN bf16
    float* xout     = (float*)(xwb + (size_t)NTOT * CIN); // B_NODES*CIN
    float* ewt      = xout + (size_t)B_NODES * CIN;       // E
    float* scalpart = ewt + E_EDGES;                      // NPART
    short* WcT      = (short*)(scalpart + NPART);         // 256*256 bf16
    short* WoT      = WcT + 256 * 256;                    // 256*512 bf16
    int*   es       = (int*)(WoT + 256 * 512);            // E
    int*   deg      = es + E_EDGES;                       // NTOT
    int*   offs     = deg + NTOT;                         // NTOT+1
    int*   blocksum = offs + NTOT + 1;                    // NBLK
    int*   blockpre = blocksum + NBLK;                    // NBLK

    hipMemsetAsync(deg, 0, sizeof(int) * NTOT, stream);
    hipMemsetAsync(scalpart, 0, sizeof(float) * NPART, stream);

    // weight transpose+convert (bf16, [n][k] layout)
    {
        dim3 g(4, 4);
        transpose_cvt_kernel<<<g, 256, 0, stream>>>(W_conv, WcT, 256, 0);
        transpose_cvt_kernel<<<g, 256, 0, stream>>>(W_t,    WoT, 512, 0);
        transpose_cvt_kernel<<<g, 256, 0, stream>>>(W_skip, WoT, 512, 256);
    }

    // CSR build
    hist_kernel<<<1024, 256, 0, stream>>>(ei, deg);
    scan_blocksum_kernel<<<NBLK, 256, 0, stream>>>(deg, blocksum);
    scan_partials_kernel<<<1, 512, 0, stream>>>(blocksum, blockpre, offs);
    scan_final_kernel<<<NBLK, 256, 0, stream>>>(deg, blockpre, offs);
    scatter_edges_kernel<<<(E_EDGES + 255) / 256, 256, 0, stream>>>(
        ei, ew, offs, deg, es, ewt);

    // xw = x_input @ W_conv (MFMA, gather fused, bf16 output)
    gemm_xinput_kernel<<<(NTOT + 63) / 64, 256, 0, stream>>>(
        x, fo, cind, cb, WcT, xwb);

    // per-destination gather + accumulate (+ fused info_backward)
    gather_accum_kernel<<<NTOT / 4, 256, 0, stream>>>(
        xwb, es, ewt, offs, b_conv, fo, cind, cb, xout, scalpart);

    // out = xout[:B] @ W_t + x @ W_skip + biases (MFMA)
    gemm_out_kernel<<<(B_NODES + 63) / 64, 256, 0, stream>>>(
        xout, x, WoT, b_t, b_skip, out);

    finalize_kernel<<<1, 256, 0, stream>>>(scalpart, wur, out);
}